// Round 5
// baseline (410.194 us; speedup 1.0000x reference)
//
#include <hip/hip_runtime.h>

// Grid_Based_network: per-row run-segmentation + top-3-energy selection.
// B=262144 rows x G=121 cols fp32. One thread per row, branch-free scan.
// grid[g] == g - 60.0f exactly (arange(-60,60,1): exact fp32 integers), so
// the weighted sum uses a register counter instead of a table lookup.

#define NROWS 262144
#define G     121
#define RCAP  61          // (G+1)/2

__global__ __launch_bounds__(256, 8)
void runs_topk_kernel(const float* __restrict__ sp,
                      const float* __restrict__ gridv,   // unused: grid[g] = g-60 exactly
                      float* __restrict__ out)
{
    const int row = blockIdx.x * 256 + threadIdx.x;
    const float* __restrict__ p = sp + (size_t)row * G;

    // streaming top-3 by energy (desc), stable: strict '>' keeps earlier run
    // on ties == jax.lax.top_k lower-index-first semantics.
    float te0 = 0.f, te1 = 0.f, te2 = 0.f;
    float tw0 = 0.f, tw1 = 0.f, tw2 = 0.f;
    int   ti0 = RCAP, ti1 = RCAP + 1, ti2 = RCAP + 2;  // virtual zero-energy slots

    float e = 0.f, w = 0.f;   // current run accumulators
    int   rid = -1;           // current run id
    bool  pm = false;         // previous element's mask
    float gval = -60.0f;      // grid value (exact)

    // fully predicated insert of candidate (ce, cw, ci); no-op when ce == 0
    // because all tracked energies are >= 0 and comparison is strict.
#define INSERT(ce, cw, ci)                                    \
    do {                                                      \
        bool c0 = (ce) > te0;                                 \
        bool c1 = (ce) > te1;                                 \
        bool c2 = (ce) > te2;                                 \
        te2 = c1 ? te1 : (c2 ? (ce) : te2);                   \
        tw2 = c1 ? tw1 : (c2 ? (cw) : tw2);                   \
        ti2 = c1 ? ti1 : (c2 ? (ci) : ti2);                   \
        te1 = c0 ? te0 : (c1 ? (ce) : te1);                   \
        tw1 = c0 ? tw0 : (c1 ? (cw) : tw1);                   \
        ti1 = c0 ? ti0 : (c1 ? (ci) : ti1);                   \
        te0 = c0 ? (ce) : te0;                                \
        tw0 = c0 ? (cw) : tw0;                                \
        ti0 = c0 ? (ci) : ti0;                                \
    } while (0)

#pragma unroll 4
    for (int g = 0; g < G; ++g) {
        float v = p[g];
        bool  m = v > 0.0f;

        // run ended at this position -> insert completed run (uses OLD e,w,rid)
        bool  endr = pm && !m;
        float ce   = endr ? e : 0.0f;
        INSERT(ce, w, rid);

        // run-state update (branch-free)
        bool  st = m && !pm;
        rid += st ? 1 : 0;
        float wv = v * gval;
        float ea = e + v;
        float wa = w + wv;
        e = m ? (st ? v  : ea) : e;
        w = m ? (st ? wv : wa) : w;
        pm = m;
        gval += 1.0f;
    }

    // final run still open at g == G-1
    {
        float ce = pm ? e : 0.0f;
        INSERT(ce, w, rid);
    }
#undef INSERT

    // sort the 3 picks by run index ascending (3-element network, predicated)
#define CSWAP(ea_, wa_, ia_, eb_, wb_, ib_)                   \
    do {                                                      \
        bool sw = ia_ > ib_;                                  \
        float t0 = ea_, t1 = wa_; int t2 = ia_;               \
        ea_ = sw ? eb_ : ea_;  eb_ = sw ? t0 : eb_;           \
        wa_ = sw ? wb_ : wa_;  wb_ = sw ? t1 : wb_;           \
        ia_ = sw ? ib_ : ia_;  ib_ = sw ? t2 : ib_;           \
    } while (0)
    CSWAP(te0, tw0, ti0, te1, tw1, ti1);
    CSWAP(te1, tw1, ti1, te2, tw2, ti2);
    CSWAP(te0, tw0, ti0, te1, tw1, ti1);
#undef CSWAP

    float* o = out + (size_t)row * 3;
    o[0] = tw0 / te0;
    o[1] = tw1 / te1;
    o[2] = tw2 / te2;
}

extern "C" void kernel_launch(void* const* d_in, const int* in_sizes, int n_in,
                              void* d_out, int out_size, void* d_ws, size_t ws_size,
                              hipStream_t stream)
{
    const float* sp    = (const float*)d_in[0];
    const float* gridv = (const float*)d_in[1];
    float*       out   = (float*)d_out;

    runs_topk_kernel<<<dim3(NROWS / 256), dim3(256), 0, stream>>>(sp, gridv, out);
}